// Round 9
// baseline (612.198 us; speedup 1.0000x reference)
//
#include <hip/hip_runtime.h>
#include <hip/hip_bf16.h>

// GATv2 x3 layers, MI355X. f32 in/out; edge_index int32.
// R9: thread-per-edge score kernel (channel-serial, in-register reduction,
// WeT/att via uniform scalar loads, ZERO shuffles/LDS) + wave-per-dst
// aggregation (softmax reduction once per NODE, not per edge).

#define NN 10000    // nodes
#define NE 200000   // edges
#define ND 128      // node dim (layer 0 input)
#define ED 16       // edge dim
#define CD 64       // conv dim (per head)
#define NH 5        // heads
#define HC 320      // NH*CD
#define EF 210000   // NE + NN (with self loops)
#define EFP 210048  // EF padded to 64
#define NEG 0.2f

// ---- CSR build: count ----
__global__ void k_count(const int* __restrict__ dst, int* __restrict__ deg) {
  int e = blockIdx.x * blockDim.x + threadIdx.x;
  if (e >= NE) return;
  atomicAdd(&deg[dst[e]], 1);
}

// ---- CSR build: exclusive scan (single block) ----
__global__ __launch_bounds__(256) void k_scan(const int* __restrict__ deg,
                                              int* __restrict__ rowptr) {
  __shared__ int part[256];
  int t = threadIdx.x;
  int base = t * 40;
  int local[40];
  int s = 0;
  #pragma unroll
  for (int j = 0; j < 40; j++) {
    int i = base + j;
    local[j] = (i < NN) ? deg[i] : 0;
    s += local[j];
  }
  part[t] = s;
  __syncthreads();
  for (int off = 1; off < 256; off <<= 1) {
    int v = (t >= off) ? part[t - off] : 0;
    __syncthreads();
    part[t] += v;
    __syncthreads();
  }
  int prefix = (t > 0) ? part[t - 1] : 0;
  #pragma unroll
  for (int j = 0; j < 40; j++) {
    int i = base + j;
    if (i < NN) rowptr[i] = prefix;
    prefix += local[j];
  }
  if (t == 255) rowptr[NN] = prefix;
}

// ---- CSR build: fill ----
__global__ void k_fill(const int* __restrict__ ei, const int* __restrict__ rowptr,
                       int* __restrict__ cursor, int* __restrict__ csr_eid,
                       int* __restrict__ csr_src, int* __restrict__ csr_dst) {
  int e = blockIdx.x * blockDim.x + threadIdx.x;
  if (e >= NE) return;
  int d = ei[NE + e];
  int slot = atomicAdd(&cursor[d], 1);
  int pos = rowptr[d] + slot;
  csr_eid[pos] = e;
  csr_src[pos] = ei[e];
  csr_dst[pos] = d;
}

// ---- loop_attr = mean of incoming edge_attr (gather, wave per node) ----
__global__ __launch_bounds__(256) void k_loopattr(const int* __restrict__ csr_eid,
                                                  const int* __restrict__ rowptr,
                                                  const float* __restrict__ eattr,
                                                  float* __restrict__ loop_attr) {
  int wave = threadIdx.x >> 6, lane = threadIdx.x & 63;
  int d = blockIdx.x * 4 + wave;
  if (d >= NN) return;
  int g = lane >> 4, k = lane & 15;
  int b = rowptr[d], n = rowptr[d + 1] - b;
  float s = 0.f;
  for (int i = g; i < n; i += 4)
    s += eattr[(size_t)csr_eid[b + i] * ED + k];
  s += __shfl_xor(s, 16, 64);
  s += __shfl_xor(s, 32, 64);
  if (g == 0) loop_attr[d * ED + k] = s / fmaxf((float)n, 1.0f);
}

// ---- ea_csr[p] = edge attrs permuted into CSR order (real edges only) ----
__global__ void k_eacsr(const int* __restrict__ csr_eid, const float* __restrict__ eattr,
                        float* __restrict__ ea_csr) {
  int idx = blockIdx.x * blockDim.x + threadIdx.x;  // (p, quad)
  if (idx >= NE * 4) return;
  int p = idx >> 2, q = idx & 3;
  const float4* sp = (const float4*)(eattr + (size_t)csr_eid[p] * ED);
  ((float4*)(ea_csr + (size_t)p * ED))[q] = sp[q];
}

// ---- WeT[hc][k] = We[k][hc]  (tiny per-layer transpose) ----
__global__ void k_wet(const float* __restrict__ We, float* __restrict__ WeT) {
  int i = blockIdx.x * blockDim.x + threadIdx.x;  // i = hc*ED + k
  if (i >= ED * HC) return;
  int hc = i >> 4, k = i & 15;
  WeT[i] = We[k * HC + hc];
}

// ---- xl = h @ Wl + bl  (no LDS; h rows via uniform broadcast loads) ----
template <int D>
__global__ __launch_bounds__(320) void k_xl(const float* __restrict__ h,
                                            const float* __restrict__ Wl,
                                            const float* __restrict__ bl,
                                            float* __restrict__ xl) {
  constexpr int NPB = 8;
  int node0 = blockIdx.x * NPB;
  int t = threadIdx.x;  // output column 0..319
  float acc[NPB];
  #pragma unroll
  for (int i = 0; i < NPB; i++) acc[i] = 0.f;
  for (int k = 0; k < D; k += 4) {
    float w0 = Wl[(k + 0) * HC + t];
    float w1 = Wl[(k + 1) * HC + t];
    float w2 = Wl[(k + 2) * HC + t];
    float w3 = Wl[(k + 3) * HC + t];
    #pragma unroll
    for (int i = 0; i < NPB; i++) {
      float4 hv = *(const float4*)(h + (size_t)(node0 + i) * D + k);
      acc[i] += hv.x * w0 + hv.y * w1 + hv.z * w2 + hv.w * w3;
    }
  }
  float bv = bl[t];
  #pragma unroll
  for (int i = 0; i < NPB; i++)
    xl[(size_t)(node0 + i) * HC + t] = acc[i] + bv;
}

__device__ __forceinline__ float dot4(float4 a, float4 b) {
  return a.x * b.x + a.y * b.y + a.z * b.z + a.w * b.w;
}

// ---- scores: ONE THREAD PER EDGE (incl. self loops). No shuffles, no LDS.
// WeT/att reads are wave-uniform -> scalar broadcast loads.
__global__ __launch_bounds__(256) void k_score(
    const int* __restrict__ csr_src, const int* __restrict__ csr_dst,
    const float* __restrict__ ea_csr, const float* __restrict__ loop_attr,
    const float* __restrict__ xl, const float* __restrict__ WeT,
    const float* __restrict__ att, float* __restrict__ scoreP) {
  int p = blockIdx.x * 256 + threadIdx.x;
  if (p >= EF) return;
  int s, d;
  const float* ea;
  if (p < NE) { s = csr_src[p]; d = csr_dst[p]; ea = ea_csr + (size_t)p * ED; }
  else        { s = d = p - NE; ea = loop_attr + (size_t)(p - NE) * ED; }
  float4 ea4[4];
  {
    const float4* q = (const float4*)ea;
    ea4[0] = q[0]; ea4[1] = q[1]; ea4[2] = q[2]; ea4[3] = q[3];
  }
  const float* xsrow = xl + (size_t)s * HC;
  const float* xdrow = xl + (size_t)d * HC;
  #pragma unroll
  for (int h = 0; h < NH; h++) {
    float sc = 0.f;
    for (int cb = 0; cb < CD; cb += 4) {  // 16 iterations
      float4 xs4 = *(const float4*)(xsrow + h * CD + cb);
      float4 xd4 = *(const float4*)(xdrow + h * CD + cb);
      const float4* w0 = (const float4*)(WeT + (h * CD + cb + 0) * ED);
      const float4* w1 = (const float4*)(WeT + (h * CD + cb + 1) * ED);
      const float4* w2 = (const float4*)(WeT + (h * CD + cb + 2) * ED);
      const float4* w3 = (const float4*)(WeT + (h * CD + cb + 3) * ED);
      float z0 = xs4.x + xd4.x + dot4(ea4[0], w0[0]) + dot4(ea4[1], w0[1]) +
                 dot4(ea4[2], w0[2]) + dot4(ea4[3], w0[3]);
      float z1 = xs4.y + xd4.y + dot4(ea4[0], w1[0]) + dot4(ea4[1], w1[1]) +
                 dot4(ea4[2], w1[2]) + dot4(ea4[3], w1[3]);
      float z2 = xs4.z + xd4.z + dot4(ea4[0], w2[0]) + dot4(ea4[1], w2[1]) +
                 dot4(ea4[2], w2[2]) + dot4(ea4[3], w2[3]);
      float z3 = xs4.w + xd4.w + dot4(ea4[0], w3[0]) + dot4(ea4[1], w3[1]) +
                 dot4(ea4[2], w3[2]) + dot4(ea4[3], w3[3]);
      z0 *= (z0 > 0.f) ? 1.0f : NEG;
      z1 *= (z1 > 0.f) ? 1.0f : NEG;
      z2 *= (z2 > 0.f) ? 1.0f : NEG;
      z3 *= (z3 > 0.f) ? 1.0f : NEG;
      float4 a4 = *(const float4*)(att + h * CD + cb);
      sc += a4.x * z0 + a4.y * z1 + a4.z * z2 + a4.w * z3;
    }
    scoreP[(size_t)h * EFP + p] = sc;
  }
}

// ---- aggregation: wave per dst; softmax reduce ONCE per node ----
__global__ __launch_bounds__(256) void k_agg(
    const int* __restrict__ csr_src, const int* __restrict__ rowptr,
    const float* __restrict__ scoreP, const float* __restrict__ xl,
    const float* __restrict__ bias, float* __restrict__ out) {
  int w = threadIdx.x >> 6, lane = threadIdx.x & 63;
  int d = blockIdx.x * 4 + w;
  if (d >= NN) return;
  int b = rowptr[d], n = rowptr[d + 1] - b;
  // self score (uniform addr -> scalar loads)
  float msc[NH];
  #pragma unroll
  for (int h = 0; h < NH; h++) msc[h] = scoreP[(size_t)h * EFP + NE + d];
  // per-head row max (lane-strided coalesced reads; reduce once per node)
  float mx[NH];
  #pragma unroll
  for (int h = 0; h < NH; h++) mx[h] = msc[h];
  for (int i = lane; i < n; i += 64) {
    #pragma unroll
    for (int h = 0; h < NH; h++)
      mx[h] = fmaxf(mx[h], scoreP[(size_t)h * EFP + b + i]);
  }
  #pragma unroll
  for (int off = 1; off < 64; off <<= 1) {
    #pragma unroll
    for (int h = 0; h < NH; h++) mx[h] = fmaxf(mx[h], __shfl_xor(mx[h], off, 64));
  }
  // init with self loop
  const float* xlL = xl + lane;
  float dn[NH], acc[NH];
  #pragma unroll
  for (int h = 0; h < NH; h++) {
    float g = __expf(msc[h] - mx[h]);
    dn[h] = g;
    acc[h] = g * xlL[(size_t)d * HC + h * CD];
  }
  // edge loop (uniform p -> scalar score loads), unroll 2
  int p = b, pe = b + n;
  for (; p + 2 <= pe; p += 2) {
    int s0 = csr_src[p], s1 = csr_src[p + 1];
    float x0[NH], x1[NH], g0[NH], g1[NH];
    #pragma unroll
    for (int h = 0; h < NH; h++) {
      x0[h] = xlL[(size_t)s0 * HC + h * CD];
      x1[h] = xlL[(size_t)s1 * HC + h * CD];
      g0[h] = __expf(scoreP[(size_t)h * EFP + p] - mx[h]);
      g1[h] = __expf(scoreP[(size_t)h * EFP + p + 1] - mx[h]);
    }
    #pragma unroll
    for (int h = 0; h < NH; h++) {
      dn[h] += g0[h] + g1[h];
      acc[h] += g0[h] * x0[h] + g1[h] * x1[h];
    }
  }
  if (p < pe) {
    int s0 = csr_src[p];
    #pragma unroll
    for (int h = 0; h < NH; h++) {
      float g = __expf(scoreP[(size_t)h * EFP + p] - mx[h]);
      dn[h] += g;
      acc[h] += g * xlL[(size_t)s0 * HC + h * CD];
    }
  }
  float v = 0.f;
  #pragma unroll
  for (int h = 0; h < NH; h++) v += acc[h] / dn[h];
  v = v * (1.0f / NH) + bias[lane];
  v = v > 0.f ? v : expm1f(v);
  out[(size_t)d * CD + lane] = v;
}

extern "C" void kernel_launch(void* const* d_in, const int* in_sizes, int n_in,
                              void* d_out, int out_size, void* d_ws, size_t ws_size,
                              hipStream_t stream) {
  const float* x = (const float*)d_in[0];
  const int* ei = (const int*)d_in[1];      // [2, NE]: src row then dst row
  const float* eattr = (const float*)d_in[2];

  char* w = (char*)d_ws;
  int* degi      = (int*)w;                 w += NN * 4;
  int* cursor    = (int*)w;                 w += NN * 4;
  int* rowptr    = (int*)w;                 w += (NN + 1) * 4;
  int* csr_eid   = (int*)w;                 w += NE * 4;
  int* csr_src   = (int*)w;                 w += NE * 4;
  int* csr_dst   = (int*)w;                 w += NE * 4;
  float* loop_attr = (float*)w;             w += (size_t)NN * ED * 4;
  float* ea_csr  = (float*)w;               w += (size_t)NE * ED * 4;
  float* xl      = (float*)w;               w += (size_t)NN * HC * 4;
  float* scoreP  = (float*)w;               w += (size_t)NH * EFP * 4;
  float* WeT     = (float*)w;               w += (size_t)ED * HC * 4;
  float* hbuf    = (float*)w;               w += (size_t)NN * CD * 4;

  // graph structure + permuted edge attrs (layer-invariant)
  hipMemsetAsync(degi, 0, NN * 4, stream);
  hipMemsetAsync(cursor, 0, NN * 4, stream);
  k_count<<<(NE + 255) / 256, 256, 0, stream>>>(ei + NE, degi);
  k_scan<<<1, 256, 0, stream>>>(degi, rowptr);
  k_fill<<<(NE + 255) / 256, 256, 0, stream>>>(ei, rowptr, cursor, csr_eid, csr_src, csr_dst);
  k_loopattr<<<(NN + 3) / 4, 256, 0, stream>>>(csr_eid, rowptr, eattr, loop_attr);
  k_eacsr<<<(NE * 4 + 255) / 256, 256, 0, stream>>>(csr_eid, eattr, ea_csr);

  for (int l = 0; l < 3; l++) {
    const float* Wl  = (const float*)d_in[3 + 5 * l];
    const float* bl  = (const float*)d_in[4 + 5 * l];
    const float* We  = (const float*)d_in[5 + 5 * l];
    const float* att = (const float*)d_in[6 + 5 * l];
    const float* b   = (const float*)d_in[7 + 5 * l];

    k_wet<<<(ED * HC + 255) / 256, 256, 0, stream>>>(We, WeT);
    if (l == 0) k_xl<ND><<<NN / 8, 320, 0, stream>>>(x, Wl, bl, xl);
    else        k_xl<CD><<<NN / 8, 320, 0, stream>>>(hbuf, Wl, bl, xl);

    k_score<<<(EF + 255) / 256, 256, 0, stream>>>(csr_src, csr_dst, ea_csr, loop_attr,
                                                  xl, WeT, att, scoreP);

    float* dst_out = (l < 2) ? hbuf : (float*)d_out;
    k_agg<<<(NN + 3) / 4, 256, 0, stream>>>(csr_src, rowptr, scoreP, xl, b, dst_out);
  }
}

// Round 10
// 574.958 us; speedup vs baseline: 1.0648x; 1.0648x over previous
//
#include <hip/hip_runtime.h>
#include <hip/hip_bf16.h>

// GATv2 x3 layers, MI355X. f32 in/out; edge_index int32.
// R10: thread-per-(edge,head) score kernel (5x TLP vs thread-per-edge; the
// R9 version had only 3.2 waves/SIMD and sat 72% idle on gather latency) +
// block-per-node/wave-per-head aggregation (LDS head combine).

#define NN 10000    // nodes
#define NE 200000   // edges
#define ND 128      // node dim (layer 0 input)
#define ED 16       // edge dim
#define CD 64       // conv dim (per head)
#define NH 5        // heads
#define HC 320      // NH*CD
#define EF 210000   // NE + NN (with self loops)
#define EFP 210048  // EF padded to 64
#define NEG 0.2f

// ---- CSR build: count ----
__global__ void k_count(const int* __restrict__ dst, int* __restrict__ deg) {
  int e = blockIdx.x * blockDim.x + threadIdx.x;
  if (e >= NE) return;
  atomicAdd(&deg[dst[e]], 1);
}

// ---- CSR build: exclusive scan (single block) ----
__global__ __launch_bounds__(256) void k_scan(const int* __restrict__ deg,
                                              int* __restrict__ rowptr) {
  __shared__ int part[256];
  int t = threadIdx.x;
  int base = t * 40;
  int local[40];
  int s = 0;
  #pragma unroll
  for (int j = 0; j < 40; j++) {
    int i = base + j;
    local[j] = (i < NN) ? deg[i] : 0;
    s += local[j];
  }
  part[t] = s;
  __syncthreads();
  for (int off = 1; off < 256; off <<= 1) {
    int v = (t >= off) ? part[t - off] : 0;
    __syncthreads();
    part[t] += v;
    __syncthreads();
  }
  int prefix = (t > 0) ? part[t - 1] : 0;
  #pragma unroll
  for (int j = 0; j < 40; j++) {
    int i = base + j;
    if (i < NN) rowptr[i] = prefix;
    prefix += local[j];
  }
  if (t == 255) rowptr[NN] = prefix;
}

// ---- CSR build: fill ----
__global__ void k_fill(const int* __restrict__ ei, const int* __restrict__ rowptr,
                       int* __restrict__ cursor, int* __restrict__ csr_eid,
                       int* __restrict__ csr_src, int* __restrict__ csr_dst) {
  int e = blockIdx.x * blockDim.x + threadIdx.x;
  if (e >= NE) return;
  int d = ei[NE + e];
  int slot = atomicAdd(&cursor[d], 1);
  int pos = rowptr[d] + slot;
  csr_eid[pos] = e;
  csr_src[pos] = ei[e];
  csr_dst[pos] = d;
}

// ---- loop_attr = mean of incoming edge_attr (gather, wave per node) ----
__global__ __launch_bounds__(256) void k_loopattr(const int* __restrict__ csr_eid,
                                                  const int* __restrict__ rowptr,
                                                  const float* __restrict__ eattr,
                                                  float* __restrict__ loop_attr) {
  int wave = threadIdx.x >> 6, lane = threadIdx.x & 63;
  int d = blockIdx.x * 4 + wave;
  if (d >= NN) return;
  int g = lane >> 4, k = lane & 15;
  int b = rowptr[d], n = rowptr[d + 1] - b;
  float s = 0.f;
  for (int i = g; i < n; i += 4)
    s += eattr[(size_t)csr_eid[b + i] * ED + k];
  s += __shfl_xor(s, 16, 64);
  s += __shfl_xor(s, 32, 64);
  if (g == 0) loop_attr[d * ED + k] = s / fmaxf((float)n, 1.0f);
}

// ---- ea_csr[p] = edge attrs permuted into CSR order (real edges only) ----
__global__ void k_eacsr(const int* __restrict__ csr_eid, const float* __restrict__ eattr,
                        float* __restrict__ ea_csr) {
  int idx = blockIdx.x * blockDim.x + threadIdx.x;  // (p, quad)
  if (idx >= NE * 4) return;
  int p = idx >> 2, q = idx & 3;
  const float4* sp = (const float4*)(eattr + (size_t)csr_eid[p] * ED);
  ((float4*)(ea_csr + (size_t)p * ED))[q] = sp[q];
}

// ---- WeT[hc][k] = We[k][hc]  (tiny per-layer transpose) ----
__global__ void k_wet(const float* __restrict__ We, float* __restrict__ WeT) {
  int i = blockIdx.x * blockDim.x + threadIdx.x;  // i = hc*ED + k
  if (i >= ED * HC) return;
  int hc = i >> 4, k = i & 15;
  WeT[i] = We[k * HC + hc];
}

// ---- xl = h @ Wl + bl  (no LDS; h rows via uniform broadcast loads) ----
template <int D>
__global__ __launch_bounds__(320) void k_xl(const float* __restrict__ h,
                                            const float* __restrict__ Wl,
                                            const float* __restrict__ bl,
                                            float* __restrict__ xl) {
  constexpr int NPB = 8;
  int node0 = blockIdx.x * NPB;
  int t = threadIdx.x;  // output column 0..319
  float acc[NPB];
  #pragma unroll
  for (int i = 0; i < NPB; i++) acc[i] = 0.f;
  for (int k = 0; k < D; k += 4) {
    float w0 = Wl[(k + 0) * HC + t];
    float w1 = Wl[(k + 1) * HC + t];
    float w2 = Wl[(k + 2) * HC + t];
    float w3 = Wl[(k + 3) * HC + t];
    #pragma unroll
    for (int i = 0; i < NPB; i++) {
      float4 hv = *(const float4*)(h + (size_t)(node0 + i) * D + k);
      acc[i] += hv.x * w0 + hv.y * w1 + hv.z * w2 + hv.w * w3;
    }
  }
  float bv = bl[t];
  #pragma unroll
  for (int i = 0; i < NPB; i++)
    xl[(size_t)(node0 + i) * HC + t] = acc[i] + bv;
}

__device__ __forceinline__ float dot4(float4 a, float4 b) {
  return a.x * b.x + a.y * b.y + a.z * b.z + a.w * b.w;
}

// ---- scores: ONE THREAD PER (EDGE, HEAD). No shuffles, no LDS.
// WeT/att reads are wave-uniform -> scalar broadcast loads.
__global__ __launch_bounds__(256) void k_score(
    const int* __restrict__ csr_src, const int* __restrict__ csr_dst,
    const float* __restrict__ ea_csr, const float* __restrict__ loop_attr,
    const float* __restrict__ xl, const float* __restrict__ WeT,
    const float* __restrict__ att, float* __restrict__ scoreP) {
  int p = blockIdx.x * 256 + threadIdx.x;
  if (p >= EF) return;
  int h = blockIdx.y;
  int s, d;
  const float* ea;
  if (p < NE) { s = csr_src[p]; d = csr_dst[p]; ea = ea_csr + (size_t)p * ED; }
  else        { s = d = p - NE; ea = loop_attr + (size_t)(p - NE) * ED; }
  float4 ea4[4];
  {
    const float4* q = (const float4*)ea;
    ea4[0] = q[0]; ea4[1] = q[1]; ea4[2] = q[2]; ea4[3] = q[3];
  }
  const float* xsrow = xl + (size_t)s * HC + h * CD;
  const float* xdrow = xl + (size_t)d * HC + h * CD;
  const float* wrow  = WeT + h * CD * ED;
  const float* arow  = att + h * CD;
  float sc = 0.f;
  #pragma unroll 4
  for (int cb = 0; cb < CD; cb += 4) {  // 16 iterations
    float4 xs4 = *(const float4*)(xsrow + cb);
    float4 xd4 = *(const float4*)(xdrow + cb);
    const float4* w0 = (const float4*)(wrow + (cb + 0) * ED);
    const float4* w1 = (const float4*)(wrow + (cb + 1) * ED);
    const float4* w2 = (const float4*)(wrow + (cb + 2) * ED);
    const float4* w3 = (const float4*)(wrow + (cb + 3) * ED);
    float z0 = xs4.x + xd4.x + dot4(ea4[0], w0[0]) + dot4(ea4[1], w0[1]) +
               dot4(ea4[2], w0[2]) + dot4(ea4[3], w0[3]);
    float z1 = xs4.y + xd4.y + dot4(ea4[0], w1[0]) + dot4(ea4[1], w1[1]) +
               dot4(ea4[2], w1[2]) + dot4(ea4[3], w1[3]);
    float z2 = xs4.z + xd4.z + dot4(ea4[0], w2[0]) + dot4(ea4[1], w2[1]) +
               dot4(ea4[2], w2[2]) + dot4(ea4[3], w2[3]);
    float z3 = xs4.w + xd4.w + dot4(ea4[0], w3[0]) + dot4(ea4[1], w3[1]) +
               dot4(ea4[2], w3[2]) + dot4(ea4[3], w3[3]);
    z0 *= (z0 > 0.f) ? 1.0f : NEG;
    z1 *= (z1 > 0.f) ? 1.0f : NEG;
    z2 *= (z2 > 0.f) ? 1.0f : NEG;
    z3 *= (z3 > 0.f) ? 1.0f : NEG;
    float4 a4 = *(const float4*)(arow + cb);
    sc += a4.x * z0 + a4.y * z1 + a4.z * z2 + a4.w * z3;
  }
  scoreP[(size_t)h * EFP + p] = sc;
}

// ---- aggregation: block per node, wave per head; LDS head-combine ----
__global__ __launch_bounds__(320) void k_agg(
    const int* __restrict__ csr_src, const int* __restrict__ rowptr,
    const float* __restrict__ scoreP, const float* __restrict__ xl,
    const float* __restrict__ bias, float* __restrict__ out) {
  __shared__ float s_v[NH][CD];
  int h = threadIdx.x >> 6, lane = threadIdx.x & 63;
  int d = blockIdx.x;
  int b = rowptr[d], n = rowptr[d + 1] - b;
  const float* sp = scoreP + (size_t)h * EFP;
  const float* xlh = xl + h * CD + lane;
  // row max (self + strided edges, reduce once)
  float msc = sp[NE + d];
  float mx = msc;
  for (int i = lane; i < n; i += 64) mx = fmaxf(mx, sp[b + i]);
  #pragma unroll
  for (int off = 1; off < 64; off <<= 1) mx = fmaxf(mx, __shfl_xor(mx, off, 64));
  // init with self loop
  float g = __expf(msc - mx);
  float dn = g;
  float acc = g * xlh[(size_t)d * HC];
  // edge loop, unroll 2 (uniform score addrs -> scalar loads)
  int p = b, pe = b + n;
  for (; p + 2 <= pe; p += 2) {
    int s0 = csr_src[p], s1 = csr_src[p + 1];
    float g0 = __expf(sp[p] - mx);
    float g1 = __expf(sp[p + 1] - mx);
    float x0 = xlh[(size_t)s0 * HC];
    float x1 = xlh[(size_t)s1 * HC];
    dn += g0 + g1;
    acc += g0 * x0 + g1 * x1;
  }
  if (p < pe) {
    int s0 = csr_src[p];
    float g0 = __expf(sp[p] - mx);
    dn += g0;
    acc += g0 * xlh[(size_t)s0 * HC];
  }
  s_v[h][lane] = acc / dn;
  __syncthreads();
  if (h == 0) {
    float v = s_v[0][lane] + s_v[1][lane] + s_v[2][lane] + s_v[3][lane] + s_v[4][lane];
    v = v * (1.0f / NH) + bias[lane];
    v = v > 0.f ? v : expm1f(v);
    out[(size_t)d * CD + lane] = v;
  }
}

extern "C" void kernel_launch(void* const* d_in, const int* in_sizes, int n_in,
                              void* d_out, int out_size, void* d_ws, size_t ws_size,
                              hipStream_t stream) {
  const float* x = (const float*)d_in[0];
  const int* ei = (const int*)d_in[1];      // [2, NE]: src row then dst row
  const float* eattr = (const float*)d_in[2];

  char* w = (char*)d_ws;
  int* degi      = (int*)w;                 w += NN * 4;
  int* cursor    = (int*)w;                 w += NN * 4;
  int* rowptr    = (int*)w;                 w += (NN + 1) * 4;
  int* csr_eid   = (int*)w;                 w += NE * 4;
  int* csr_src   = (int*)w;                 w += NE * 4;
  int* csr_dst   = (int*)w;                 w += NE * 4;
  float* loop_attr = (float*)w;             w += (size_t)NN * ED * 4;
  float* ea_csr  = (float*)w;               w += (size_t)NE * ED * 4;
  float* xl      = (float*)w;               w += (size_t)NN * HC * 4;
  float* scoreP  = (float*)w;               w += (size_t)NH * EFP * 4;
  float* WeT     = (float*)w;               w += (size_t)ED * HC * 4;
  float* hbuf    = (float*)w;               w += (size_t)NN * CD * 4;

  // graph structure + permuted edge attrs (layer-invariant)
  hipMemsetAsync(degi, 0, NN * 4, stream);
  hipMemsetAsync(cursor, 0, NN * 4, stream);
  k_count<<<(NE + 255) / 256, 256, 0, stream>>>(ei + NE, degi);
  k_scan<<<1, 256, 0, stream>>>(degi, rowptr);
  k_fill<<<(NE + 255) / 256, 256, 0, stream>>>(ei, rowptr, cursor, csr_eid, csr_src, csr_dst);
  k_loopattr<<<(NN + 3) / 4, 256, 0, stream>>>(csr_eid, rowptr, eattr, loop_attr);
  k_eacsr<<<(NE * 4 + 255) / 256, 256, 0, stream>>>(csr_eid, eattr, ea_csr);

  for (int l = 0; l < 3; l++) {
    const float* Wl  = (const float*)d_in[3 + 5 * l];
    const float* bl  = (const float*)d_in[4 + 5 * l];
    const float* We  = (const float*)d_in[5 + 5 * l];
    const float* att = (const float*)d_in[6 + 5 * l];
    const float* b   = (const float*)d_in[7 + 5 * l];

    k_wet<<<(ED * HC + 255) / 256, 256, 0, stream>>>(We, WeT);
    if (l == 0) k_xl<ND><<<NN / 8, 320, 0, stream>>>(x, Wl, bl, xl);
    else        k_xl<CD><<<NN / 8, 320, 0, stream>>>(hbuf, Wl, bl, xl);

    dim3 gs((EF + 255) / 256, NH);
    k_score<<<gs, 256, 0, stream>>>(csr_src, csr_dst, ea_csr, loop_attr,
                                    xl, WeT, att, scoreP);

    float* dst_out = (l < 2) ? hbuf : (float*)d_out;
    k_agg<<<NN, 320, 0, stream>>>(csr_src, rowptr, scoreP, xl, b, dst_out);
  }
}